// Round 3
// baseline (183.553 us; speedup 1.0000x reference)
//
#include <hip/hip_runtime.h>
#include <math.h>

#define NF 128
#define NT 32
#define NS 32
#define ATILE 64        // nodes per block; 200000 = 3125 * 64 exactly
#define ABLOCKS 3125
#define VSTRIDE 136     // v LDS row stride in shorts: 272 B, 16B-aligned, 2-way banks (free)
#define HPAD 33         // corr row stride; (t*33+s)%32 = (t+s)%32 decorrelates banks

typedef short bf16x8 __attribute__((ext_vector_type(8)));
typedef float floatx4 __attribute__((ext_vector_type(4)));

__device__ __forceinline__ float rcp_fast(float x) { return __builtin_amdgcn_rcpf(x); }

// split fp32 into bf16 hi + bf16 lo (RTN both): f ~= hi + lo to ~2^-17 rel
// (proven path from the round-0 kernel; no inline asm)
__device__ __forceinline__ void split_bf16(float f, unsigned short& h, unsigned short& l) {
    unsigned u  = __float_as_uint(f);
    unsigned r  = u + 0x7FFFu + ((u >> 16) & 1u);
    unsigned hb = r & 0xFFFF0000u;
    h = (unsigned short)(hb >> 16);
    float rem = f - __uint_as_float(hb);
    unsigned u2 = __float_as_uint(rem);
    unsigned r2 = u2 + 0x7FFFu + ((u2 >> 16) & 1u);
    l = (unsigned short)(r2 >> 16);
}

__device__ __forceinline__ void split8(float4 a, float4 b, bf16x8& h8, bf16x8& l8) {
    unsigned short h[8], l[8];
    split_bf16(a.x, h[0], l[0]); split_bf16(a.y, h[1], l[1]);
    split_bf16(a.z, h[2], l[2]); split_bf16(a.w, h[3], l[3]);
    split_bf16(b.x, h[4], l[4]); split_bf16(b.y, h[5], l[5]);
    split_bf16(b.z, h[6], l[6]); split_bf16(b.w, h[7], l[7]);
    h8 = (bf16x8){(short)h[0],(short)h[1],(short)h[2],(short)h[3],
                  (short)h[4],(short)h[5],(short)h[6],(short)h[7]};
    l8 = (bf16x8){(short)l[0],(short)l[1],(short)l[2],(short)l[3],
                  (short)l[4],(short)l[5],(short)l[6],(short)l[7]};
}

__global__ __launch_bounds__(256, 7)   // ~21.9 KB LDS -> 7 blocks/CU
void ect_fused(const float* __restrict__ x,
               const int* __restrict__ batch,
               const float* __restrict__ v,
               float* __restrict__ out)
{
    __shared__ __align__(16) unsigned short vh[NT * VSTRIDE];  // 8704 B; reused as queue after GEMM
    __shared__ __align__(16) unsigned short vl[NT * VSTRIDE];  // 8704 B
    __shared__ int   batch_lds[ATILE];                         //  256 B
    __shared__ float corr[NT * HPAD];                          // 4224 B (difference-domain accumulator)
    __shared__ float cnt_lds;
    __shared__ int   qcnt[4];                                  // per-wave queue lengths

    const int tid  = threadIdx.x;
    const int blk  = blockIdx.x;
    const int w    = tid >> 6;
    const int lane = tid & 63;
    const int mrow = lane & 15;
    const int quad = lane >> 4;

    // ---- stage v -> bf16 hi/lo in LDS (32 rows x 32 float4) ----
    #pragma unroll
    for (int j = 0; j < 4; ++j) {
        int idx4 = j * 256 + tid;
        int row  = idx4 >> 5;
        int f4   = idx4 & 31;
        float4 val = *(const float4*)&v[(size_t)row * NF + f4 * 4];
        unsigned short h0,h1,h2,h3,l0,l1,l2,l3;
        split_bf16(val.x, h0, l0); split_bf16(val.y, h1, l1);
        split_bf16(val.z, h2, l2); split_bf16(val.w, h3, l3);
        uint2 hh, ll;
        hh.x = (unsigned)h0 | ((unsigned)h1 << 16); hh.y = (unsigned)h2 | ((unsigned)h3 << 16);
        ll.x = (unsigned)l0 | ((unsigned)l1 << 16); ll.y = (unsigned)l2 | ((unsigned)l3 << 16);
        *(uint2*)&vh[row * VSTRIDE + f4 * 4] = hh;
        *(uint2*)&vl[row * VSTRIDE + f4 * 4] = ll;
    }
    if (tid < ATILE) batch_lds[tid] = batch[blk * ATILE + tid];

    // ---- A fragments straight from global: lane owns x row (w*16 + mrow) ----
    const size_t arow = (size_t)blk * ATILE + w * 16 + mrow;
    const float* __restrict__ xrow = x + arow * NF + quad * 8;

    floatx4 acc0 = {0.f, 0.f, 0.f, 0.f};   // thetas 0..15  (col = mrow)
    floatx4 acc1 = {0.f, 0.f, 0.f, 0.f};   // thetas 16..31

    bf16x8 ah[4], al[4];
    #pragma unroll
    for (int slice = 0; slice < 4; ++slice) {
        float4 a0 = *(const float4*)&xrow[slice * 32];
        float4 a1 = *(const float4*)&xrow[slice * 32 + 4];
        split8(a0, a1, ah[slice], al[slice]);
    }
    __syncthreads();   // vh/vl + batch_lds ready

    const int b0base = mrow * VSTRIDE + quad * 8;
    const int b1base = (16 + mrow) * VSTRIDE + quad * 8;
    #pragma unroll
    for (int slice = 0; slice < 4; ++slice) {
        bf16x8 bh0 = *(bf16x8*)&vh[b0base + slice * 32];
        bf16x8 bl0 = *(bf16x8*)&vl[b0base + slice * 32];
        bf16x8 bh1 = *(bf16x8*)&vh[b1base + slice * 32];
        bf16x8 bl1 = *(bf16x8*)&vl[b1base + slice * 32];
        acc0 = __builtin_amdgcn_mfma_f32_16x16x32_bf16(ah[slice], bh0, acc0, 0, 0, 0);
        acc0 = __builtin_amdgcn_mfma_f32_16x16x32_bf16(ah[slice], bl0, acc0, 0, 0, 0);
        acc0 = __builtin_amdgcn_mfma_f32_16x16x32_bf16(al[slice], bh0, acc0, 0, 0, 0);
        acc1 = __builtin_amdgcn_mfma_f32_16x16x32_bf16(ah[slice], bh1, acc1, 0, 0, 0);
        acc1 = __builtin_amdgcn_mfma_f32_16x16x32_bf16(ah[slice], bl1, acc1, 0, 0, 0);
        acc1 = __builtin_amdgcn_mfma_f32_16x16x32_bf16(al[slice], bh1, acc1, 0, 0, 0);
    }
    __syncthreads();   // all vh/vl fragment reads done -> vh reusable as queue
    // C/D layout: col = lane&15 (theta), row = quad*4 + reg (node-in-16-tile)

    float* qf = (float*)vh;                     // 2048-entry float queue, 512 per wave

    const float inv_dlin = 14.090909090909092f; // 31/2.2
    const float Lw       = 10.23848093f;        // SCALE * dlin * log2(e)
    const float dlin     = 2.2f / 31.0f;
    const float L        = 144.26950408889634f; // SCALE * log2(e)
    const float C1       = 8.2777115e-04f;      // 2^-Lw = exp(-SCALE*dlin)

    const int g_first = batch_lds[0];
    const int g_last  = batch_lds[ATILE - 1];

    // flush ownership: thread -> (t = ft, s = sb + 8k); pad sigmoid hoisted (s fixed per thread)
    const int ft = tid & 31;
    const int sb = tid >> 5;
    float csk[4];
    #pragma unroll
    for (int k = 0; k < 4; ++k) {
        int s = sb + 8 * k;
        float lin_s = -1.1f + (float)s * dlin;
        csk[k] = rcp_fast(1.0f + __builtin_amdgcn_exp2f(L * (1.1f - lin_s)));
    }

    // zt encodes (z, t) in one float: zt = z + 64*t + 16, z = (h+1.1)/dlin in [-1.45, 32.45]
    const float cH0 = 31.5f + 64.0f * (float)mrow;         // fma const for t = mrow
    const float cH1 = cH0 + 1024.0f;                       // t = 16 + mrow
    const float lo0 = cH0 - 16.95f, hi0 = cH0 + 16.95f;    // z <= -1.45  /  z >= 32.45
    const float lo1 = cH1 - 16.95f, hi1 = cH1 + 16.95f;

    for (int gp = g_first; gp <= g_last; ++gp) {   // 96% of tiles: single pass
        // ---- phase 1: clear corr, classify 8 elements, ballot-compact in-window into queue ----
        for (int i = tid; i < NT * HPAD; i += 256) corr[i] = 0.0f;
        if (tid < ATILE) {
            unsigned long long m2 = __ballot(batch_lds[tid] == gp);
            if (tid == 0) cnt_lds = (float)__popcll(m2);
        }
        int wbase = w * 512;
        int c0 = 0, c1 = 0;      // saturated-low counts (sigmoid ~ 1 over whole grid)
        #pragma unroll
        for (int reg = 0; reg < 4; ++reg) {
            bool ok = (batch_lds[w * 16 + quad * 4 + reg] == gp);
            {   // half 0: t = mrow
                float zt = fmaf(acc0[reg], inv_dlin, cH0);
                bool full = ok && (zt > lo0) && (zt < hi0);
                unsigned long long m = __ballot(full);
                int pos = __builtin_amdgcn_mbcnt_hi((unsigned)(m >> 32),
                          __builtin_amdgcn_mbcnt_lo((unsigned)m, 0));
                if (full) qf[wbase + pos] = zt;
                wbase += __popcll(m);
                c0 += (ok && (zt <= lo0)) ? 1 : 0;
            }
            {   // half 1: t = 16 + mrow
                float zt = fmaf(acc1[reg], inv_dlin, cH1);
                bool full = ok && (zt > lo1) && (zt < hi1);
                unsigned long long m = __ballot(full);
                int pos = __builtin_amdgcn_mbcnt_hi((unsigned)(m >> 32),
                          __builtin_amdgcn_mbcnt_lo((unsigned)m, 0));
                if (full) qf[wbase + pos] = zt;
                wbase += __popcll(m);
                c1 += (ok && (zt <= lo1)) ? 1 : 0;
            }
        }
        if (lane == 0) qcnt[w] = wbase - w * 512;
        __syncthreads();

        // ---- phase 2: low counts + drain queue; deposit sigmoid DIFFERENCES (prefix-scan
        //      reconstructs sig exactly; d0+d1+d2+d3 = 1 so the step part is free) ----
        if (c0) atomicAdd(&corr[mrow * HPAD], (float)c0);
        if (c1) atomicAdd(&corr[(16 + mrow) * HPAD], (float)c1);
        for (int seg = 0; seg < 4; ++seg) {
            const int ne = qcnt[seg];
            for (int i = tid; i < ne; i += 256) {
                float zt  = qf[seg * 512 + i];
                float tf  = floorf(zt * 0.015625f);            // t (frac in [0.227,0.757]: safe)
                float z   = fmaf(tf, -64.0f, zt) - 16.0f;
                int   b   = (int)tf * HPAD;
                float s0f = ceilf(z - 1.45f);                  // s0 in [-2, 31]
                int   s0  = (int)s0f;
                float e0  = __builtin_amdgcn_exp2f(Lw * (z - s0f));  // 2^[4.6,14.85]
                float e1  = e0 * C1;
                float e2  = e1 * C1;
                float f0  = rcp_fast(1.0f + e0);
                float f1  = rcp_fast(1.0f + e1);
                float f2  = rcp_fast(1.0f + e2);
                int sA = max(s0, 0);
                atomicAdd(&corr[b + sA], f0);                  // s0 <= 31 always
                int sB = max(s0 + 1, 0);
                if (sB < 32) atomicAdd(&corr[b + sB], f1 - f0);
                int sC = max(s0 + 2, 0);
                if (sC < 32) atomicAdd(&corr[b + sC], f2 - f1);
                int sD = s0 + 3;                               // >= 1 always
                if (sD < 32) atomicAdd(&corr[b + sD], 1.0f - f2);
            }
        }
        __syncthreads();

        // ---- inclusive prefix-scan each theta row of corr in place -> final partial sums ----
        {
            const int grp = tid >> 5;   // 8 groups x 32 lanes; group handles rows grp+8i
            const int sc  = tid & 31;
            for (int row = grp; row < NT; row += 8) {
                float val = corr[row * HPAD + sc];
                #pragma unroll
                for (int d = 1; d < 32; d <<= 1) {
                    float nbr = __shfl_up(val, d, 32);
                    if (sc >= d) val += nbr;
                }
                corr[row * HPAD + sc] = val;
            }
        }
        __syncthreads();

        // ---- flush: subtract exact pad term cnt * sigmoid(SCALE*(lin_s - R)) ----
        #pragma unroll
        for (int k = 0; k < 4; ++k) {
            int s = sb + 8 * k;
            float val = corr[ft * HPAD + s] - cnt_lds * csk[k];
            atomicAdd(&out[(size_t)gp * (NS * NT) + s * NT + ft], val);
        }
        if (gp < g_last) __syncthreads();
    }
}

extern "C" void kernel_launch(void* const* d_in, const int* in_sizes, int n_in,
                              void* d_out, int out_size, void* d_ws, size_t ws_size,
                              hipStream_t stream) {
    const float* x     = (const float*)d_in[0];
    const int*   batch = (const int*)d_in[1];
    const float* v     = (const float*)d_in[3];
    float*       out   = (float*)d_out;

    hipMemsetAsync(d_out, 0, (size_t)out_size * sizeof(float), stream);
    ect_fused<<<dim3(ABLOCKS), dim3(256), 0, stream>>>(x, batch, v, out);
}